// Round 1
// baseline (428.879 us; speedup 1.0000x reference)
//
#include <hip/hip_runtime.h>
#include <hip/hip_bf16.h>

// Problem constants
#define S_DIM 1024
#define N_DIM 4096
#define M_DIM 4096
// RANK = 64, LORA_ALPHA = 0.8, CODEBOOK_SCALE = 1.03

typedef float  floatx4 __attribute__((ext_vector_type(4)));
typedef short  bf16x8  __attribute__((ext_vector_type(8)));

__device__ __forceinline__ unsigned short f2bf_rne(float f) {
  union { float f; unsigned int u; } v; v.f = f;
  unsigned int r = v.u + 0x7FFFu + ((v.u >> 16) & 1u);
  return (unsigned short)(r >> 16);
}

// ---------------------------------------------------------------------------
// Kernel 1: decode E8P codes -> integer-scaled weights, stored exactly in bf16.
// true w = I / (4*1.03), I = 2*s*nib + (2*shift-1), |I| <= 29 (exact in bf16).
// Wd layout: [M][N] row-major, code (m,g) -> cols 8g..8g+7.
// ---------------------------------------------------------------------------
__global__ void decode_kernel(const int* __restrict__ codes,
                              const int* __restrict__ grid,
                              unsigned short* __restrict__ Wd) {
  __shared__ int sgrid[256];
  int t = threadIdx.x;
  sgrid[t] = grid[t & 255];
  __syncthreads();
  int idx = blockIdx.x * 256 + t;            // 0 .. 4096*512-1
  int c = codes[idx];
  int abs_idx   = c & 255;
  int sign_bits = (c >> 8) & 127;
  int dlt       = 2 * ((c >> 15) & 1) - 1;   // 4*delta = ±1
  int packed    = sgrid[abs_idx];
  int par       = __popc(sign_bits) & 1;     // parity -> 8th sign
  unsigned short w[8];
#pragma unroll
  for (int j = 0; j < 8; ++j) {
    int nib = (packed >> (4 * j)) & 15;
    int neg = (j < 7) ? ((sign_bits >> j) & 1) : par;
    int val = (neg ? -2 * nib : 2 * nib) + dlt;
    w[j] = f2bf_rne((float)val);             // exact: |val| <= 29
  }
  uint4 pk;
  pk.x = (unsigned)w[0] | ((unsigned)w[1] << 16);
  pk.y = (unsigned)w[2] | ((unsigned)w[3] << 16);
  pk.z = (unsigned)w[4] | ((unsigned)w[5] << 16);
  pk.w = (unsigned)w[6] | ((unsigned)w[7] << 16);
  ((uint4*)Wd)[idx] = pk;
}

// ---------------------------------------------------------------------------
// Kernel 2: u[s,:] = bf16( FWHT_norm( x[s,:] * SU ) )   (length-4096 rows)
// ---------------------------------------------------------------------------
__global__ void fwht_u_kernel(const float* __restrict__ x,
                              const float* __restrict__ SU,
                              unsigned short* __restrict__ u) {
  __shared__ float row[4096];
  int s = blockIdx.x, t = threadIdx.x;       // 256 threads
  const float* xr = x + (size_t)s * 4096;
  for (int i = t; i < 4096; i += 256) row[i] = xr[i] * SU[i];
  __syncthreads();
  for (int h = 1; h < 4096; h <<= 1) {
    for (int p = t; p < 2048; p += 256) {
      int i = ((p & ~(h - 1)) << 1) | (p & (h - 1));
      float a = row[i], b = row[i + h];
      row[i] = a + b; row[i + h] = a - b;
    }
    __syncthreads();
  }
  unsigned short* ur = u + (size_t)s * 4096;
  for (int i = t; i < 4096; i += 256) ur[i] = f2bf_rne(row[i] * 0.015625f); // /64
}

// ---------------------------------------------------------------------------
// Kernel 3: z = u * Wd^T   (bf16 MFMA GEMM, A=[S,K] B^T=[M,K] row-major, K=4096)
// 128x128 tile, BK=32, 4 waves, 4x4 16x16x32 frags per wave.
// ---------------------------------------------------------------------------
#define BM 128
#define BN 128
#define BK 32
#define LDSP 40   // padded pitch (bf16) -> 2-way bank aliasing only (free)

__global__ __launch_bounds__(256) void gemm_kernel(
    const unsigned short* __restrict__ A,   // u  [1024][4096]
    const unsigned short* __restrict__ B,   // Wd [4096][4096]
    float* __restrict__ Z) {                // z  [1024][4096]
  __shared__ unsigned short sA[BM][LDSP];
  __shared__ unsigned short sB[BN][LDSP];
  int t  = threadIdx.x;
  int m0 = blockIdx.x * BN;                 // 0..31
  int s0 = blockIdx.y * BM;                 // 0..7
  int w = t >> 6, lane = t & 63;
  int wm = w >> 1, wn = w & 1;
  int lr16 = lane & 15, lk = lane >> 4;     // k-group: k = lk*8 + j

  floatx4 acc[4][4];
#pragma unroll
  for (int i = 0; i < 4; ++i)
#pragma unroll
    for (int j = 0; j < 4; ++j) acc[i][j] = (floatx4){0.f, 0.f, 0.f, 0.f};

  for (int kt = 0; kt < 4096; kt += BK) {
#pragma unroll
    for (int i = 0; i < 2; ++i) {           // 512 segments of 8 bf16 per operand
      int seg = t + 256 * i;
      int row = seg >> 2, sc = seg & 3;
      *(uint4*)&sA[row][sc * 8] =
          *(const uint4*)(A + (size_t)(s0 + row) * 4096 + kt + sc * 8);
      *(uint4*)&sB[row][sc * 8] =
          *(const uint4*)(B + (size_t)(m0 + row) * 4096 + kt + sc * 8);
    }
    __syncthreads();
    bf16x8 a[4], b[4];
#pragma unroll
    for (int i = 0; i < 4; ++i) a[i] = *(const bf16x8*)&sA[wm * 64 + i * 16 + lr16][lk * 8];
#pragma unroll
    for (int j = 0; j < 4; ++j) b[j] = *(const bf16x8*)&sB[wn * 64 + j * 16 + lr16][lk * 8];
#pragma unroll
    for (int i = 0; i < 4; ++i)
#pragma unroll
      for (int j = 0; j < 4; ++j)
        acc[i][j] = __builtin_amdgcn_mfma_f32_16x16x32_bf16(a[i], b[j], acc[i][j], 0, 0, 0);
    __syncthreads();
  }
  // epilogue: C/D layout col = lane&15, row = (lane>>4)*4 + q  [m89/m91]
#pragma unroll
  for (int i = 0; i < 4; ++i) {
#pragma unroll
    for (int j = 0; j < 4; ++j) {
      int col  = m0 + wn * 64 + j * 16 + lr16;
      int rowb = s0 + wm * 64 + i * 16 + lk * 4;
#pragma unroll
      for (int q = 0; q < 4; ++q)
        Z[(size_t)(rowb + q) * 4096 + col] = acc[i][j][q];
    }
  }
}

// ---------------------------------------------------------------------------
// Kernel 4: lr[s,r] = sum_n x[s,n] * loraB[r,n]   (RANK=64)
// ---------------------------------------------------------------------------
__global__ void lora_lr_kernel(const float* __restrict__ x,
                               const float* __restrict__ loraB,
                               float* __restrict__ lr) {
  __shared__ float xs[4096];
  __shared__ float red[64][4];
  int s = blockIdx.x, t = threadIdx.x;      // 256 threads
  const float* xr = x + (size_t)s * 4096;
  for (int i = t; i < 4096; i += 256) xs[i] = xr[i];
  __syncthreads();
  int r = t >> 2, q = t & 3;
  const float4* B4 = (const float4*)(loraB + (size_t)r * 4096 + q * 1024);
  const float4* x4 = (const float4*)(xs + q * 1024);
  float acc = 0.f;
#pragma unroll 4
  for (int i = 0; i < 256; ++i) {
    float4 bv = B4[i], xv = x4[i];
    acc += bv.x * xv.x + bv.y * xv.y + bv.z * xv.z + bv.w * xv.w;
  }
  red[r][q] = acc;
  __syncthreads();
  if (t < 64) lr[(size_t)s * 64 + t] = red[t][0] + red[t][1] + red[t][2] + red[t][3];
}

// ---------------------------------------------------------------------------
// Kernel 5: out[s,m] = SV[m]*Wscale/(64*4*1.03) * FWHT(z[s,:])[m]
//                      + 0.8 * sum_r lr[s,r]*loraA[m,r]
// z aliases d_out: full row is read into LDS (+sync) before any write.
// ---------------------------------------------------------------------------
__global__ void final_kernel(const float* __restrict__ Z,
                             const float* __restrict__ SV,
                             const float* __restrict__ WscaleP,
                             const float* __restrict__ loraA,
                             const float* __restrict__ lr,
                             float* __restrict__ out) {
  __shared__ float row[4096];
  __shared__ float lrs[64];
  int s = blockIdx.x, t = threadIdx.x;      // 256 threads
  const float* zr = Z + (size_t)s * 4096;
  for (int i = t; i < 4096; i += 256) row[i] = zr[i];
  if (t < 64) lrs[t] = lr[(size_t)s * 64 + t];
  __syncthreads();
  for (int h = 1; h < 4096; h <<= 1) {
    for (int p = t; p < 2048; p += 256) {
      int i = ((p & ~(h - 1)) << 1) | (p & (h - 1));
      float a = row[i], b = row[i + h];
      row[i] = a + b; row[i + h] = a - b;
    }
    __syncthreads();
  }
  float gscale = WscaleP[0] * (1.0f / (64.0f * 4.0f * 1.03f));
  float* orow = out + (size_t)s * 4096;
  for (int m = t; m < 4096; m += 256) {
    const float4* la = (const float4*)(loraA + (size_t)m * 64);
    float dot = 0.f;
#pragma unroll
    for (int r4 = 0; r4 < 16; ++r4) {
      float4 av = la[r4];
      dot += av.x * lrs[r4 * 4] + av.y * lrs[r4 * 4 + 1] +
             av.z * lrs[r4 * 4 + 2] + av.w * lrs[r4 * 4 + 3];
    }
    orow[m] = row[m] * gscale * SV[m] + 0.8f * dot;
  }
}

// ---------------------------------------------------------------------------
extern "C" void kernel_launch(void* const* d_in, const int* in_sizes, int n_in,
                              void* d_out, int out_size, void* d_ws, size_t ws_size,
                              hipStream_t stream) {
  const float* x      = (const float*)d_in[0];   // [1,1024,4096]
  const float* SU     = (const float*)d_in[1];   // [4096]
  const float* SV     = (const float*)d_in[2];   // [4096]
  const float* Wscale = (const float*)d_in[3];   // scalar
  const float* loraA  = (const float*)d_in[4];   // [4096,64]
  const float* loraB  = (const float*)d_in[5];   // [64,4096]
  const int*   Qidxs  = (const int*)d_in[6];     // [4096,512]
  const int*   grid   = (const int*)d_in[7];     // [256]
  float* out = (float*)d_out;

  char* ws = (char*)d_ws;
  unsigned short* Wd = (unsigned short*)ws;                       // 32 MB
  unsigned short* u  = (unsigned short*)(ws + (33554432));        //  8 MB
  float* lrbuf       = (float*)(ws + 33554432 + 8388608);         // 256 KB
  float* z           = out;  // z aliases d_out (final_kernel reads-then-writes per row)

  decode_kernel<<<8192, 256, 0, stream>>>(Qidxs, grid, Wd);
  fwht_u_kernel<<<1024, 256, 0, stream>>>(x, SU, u);
  lora_lr_kernel<<<1024, 256, 0, stream>>>(x, loraB, lrbuf);
  dim3 gg(32, 8);
  gemm_kernel<<<gg, 256, 0, stream>>>(u, Wd, z);
  final_kernel<<<1024, 256, 0, stream>>>(z, SV, Wscale, loraA, lrbuf, out);
}

// Round 2
// 129.959 us; speedup vs baseline: 3.3001x; 3.3001x over previous
//
#include <hip/hip_runtime.h>
#include <hip/hip_bf16.h>

typedef unsigned short u16;
typedef float  floatx4 __attribute__((ext_vector_type(4)));
typedef short  bf16x8  __attribute__((ext_vector_type(8)));

#define GK 4160   // extended K = 4096 + 64 lora cols

__device__ __forceinline__ u16 f2bf_rne(float f) {
  union { float f; unsigned int u; } v; v.f = f;
  unsigned int r = v.u + 0x7FFFu + ((v.u >> 16) & 1u);
  return (u16)(r >> 16);
}

// ===========================================================================
// In-register FWHT-4096 per block: H4096 = H64(rows r) (x) H64(cols c),
// i = r*64 + c. Wave w (of 4) holds r = w*16+k, lane l holds c = l.
// Step 1: FWHT over c via 6 shfl_xor stages. Step 2: FWHT over r:
// bits 4-5 via one LDS exchange (1 barrier), bits 0-3 in registers.
// ===========================================================================
__device__ __forceinline__ void fwht4096_regs(float v[16], float* X, int w, int l) {
#pragma unroll
  for (int h = 1; h < 64; h <<= 1) {
#pragma unroll
    for (int k = 0; k < 16; ++k) {
      float o = __shfl_xor(v[k], h, 64);
      v[k] = (l & h) ? (o - v[k]) : (v[k] + o);
    }
  }
#pragma unroll
  for (int k = 0; k < 16; ++k) X[(w * 16 + k) * 64 + l] = v[k];
  __syncthreads();
  float s4 = (w & 1) ? -1.f : 1.f;
  float s5 = (w & 2) ? -1.f : 1.f;
#pragma unroll
  for (int k = 0; k < 16; ++k) {
    float x00 = X[(k     ) * 64 + l];
    float x01 = X[(k + 16) * 64 + l];
    float x10 = X[(k + 32) * 64 + l];
    float x11 = X[(k + 48) * 64 + l];
    v[k] = (x00 + s4 * x01) + s5 * (x10 + s4 * x11);
  }
#pragma unroll
  for (int h = 1; h < 16; h <<= 1) {
#pragma unroll
    for (int k = 0; k < 16; ++k) {
      if (!(k & h)) { float a = v[k], b = v[k ^ h]; v[k] = a + b; v[k ^ h] = a - b; }
    }
  }
}

// ---------------------------------------------------------------------------
// Kernel 1: decode E8P -> integer weights (exact in bf16), pitched rows of GK.
// ---------------------------------------------------------------------------
__global__ void decode_kernel(const int* __restrict__ codes,
                              const int* __restrict__ grid,
                              u16* __restrict__ Wd) {
  __shared__ int sgrid[256];
  int t = threadIdx.x;
  sgrid[t] = grid[t & 255];
  __syncthreads();
  int idx = blockIdx.x * 256 + t;            // 0 .. 4096*512-1
  int c = codes[idx];
  int abs_idx   = c & 255;
  int sign_bits = (c >> 8) & 127;
  int dlt       = 2 * ((c >> 15) & 1) - 1;   // 4*delta = ±1
  int packed    = sgrid[abs_idx];
  int par       = __popc(sign_bits) & 1;
  u16 w[8];
#pragma unroll
  for (int j = 0; j < 8; ++j) {
    int nib = (packed >> (4 * j)) & 15;
    int neg = (j < 7) ? ((sign_bits >> j) & 1) : par;
    int val = (neg ? -2 * nib : 2 * nib) + dlt;
    w[j] = f2bf_rne((float)val);             // exact: |val| <= 29
  }
  uint4 pk;
  pk.x = (unsigned)w[0] | ((unsigned)w[1] << 16);
  pk.y = (unsigned)w[2] | ((unsigned)w[3] << 16);
  pk.z = (unsigned)w[4] | ((unsigned)w[5] << 16);
  pk.w = (unsigned)w[6] | ((unsigned)w[7] << 16);
  int m = idx >> 9, g = idx & 511;
  ((uint4*)Wd)[(size_t)m * (GK / 8) + g] = pk;   // GK/8 = 520 uint4 per row
}

// ---------------------------------------------------------------------------
// Kernel 2: At[r][m] = bf16( (0.8*263.68/(4096*Wscale)) * H_M(SV o loraA[:,r]) )
// ---------------------------------------------------------------------------
__global__ __launch_bounds__(256) void prep_A_kernel(const float* __restrict__ loraA,
                                                     const float* __restrict__ SV,
                                                     const float* __restrict__ WscaleP,
                                                     u16* __restrict__ At) {
  __shared__ float X[4096];
  int r = blockIdx.x, t = threadIdx.x, l = t & 63, w = t >> 6;
  float v[16];
#pragma unroll
  for (int k = 0; k < 16; ++k) {
    int i = (w * 16 + k) * 64 + l;
    v[k] = loraA[(size_t)i * 64 + r] * SV[i];
  }
  fwht4096_regs(v, X, w, l);
  float factor = (0.8f * 263.68f / 4096.0f) / WscaleP[0];
#pragma unroll
  for (int k = 0; k < 16; ++k) {
    int i = (w * 16 + k) * 64 + l;
    At[(size_t)r * 4096 + i] = f2bf_rne(v[k] * factor);
  }
}

// ---------------------------------------------------------------------------
// Kernel 3: transpose At[64][4096] into Wd_ext tail cols: Wd[m][4096+r]
// ---------------------------------------------------------------------------
__global__ void transA_kernel(const u16* __restrict__ At, u16* __restrict__ Wd) {
  __shared__ u16 T[64][65];
  int m0 = blockIdx.x * 64, t = threadIdx.x;
  int c = t & 63, q = t >> 6;
#pragma unroll
  for (int j = 0; j < 16; ++j) {
    int r = q * 16 + j;
    T[r][c] = At[(size_t)r * 4096 + m0 + c];
  }
  __syncthreads();
#pragma unroll
  for (int j = 0; j < 16; ++j) {
    int m = q * 16 + j;
    Wd[(size_t)(m0 + m) * GK + 4096 + c] = T[c][m];
  }
}

// ---------------------------------------------------------------------------
// Kernel 4: u_ext[s][0..4095] = bf16( H(x[s] o SU) / 64 )
// ---------------------------------------------------------------------------
__global__ __launch_bounds__(256) void fwht_u_kernel(const float* __restrict__ x,
                                                     const float* __restrict__ SU,
                                                     u16* __restrict__ u) {
  __shared__ float X[4096];
  int s = blockIdx.x, t = threadIdx.x, l = t & 63, w = t >> 6;
  const float* xr = x + (size_t)s * 4096;
  float v[16];
#pragma unroll
  for (int k = 0; k < 16; ++k) {
    int i = (w * 16 + k) * 64 + l;
    v[k] = xr[i] * SU[i];
  }
  fwht4096_regs(v, X, w, l);
  u16* ur = u + (size_t)s * GK;
#pragma unroll
  for (int k = 0; k < 16; ++k) {
    int i = (w * 16 + k) * 64 + l;
    ur[i] = f2bf_rne(v[k] * 0.015625f);
  }
}

// ---------------------------------------------------------------------------
// Kernel 5: lr[s,r] = sum_n x[s,n]*loraB[r,n], 4 s-rows per block, bf16 into
// u_ext tail cols 4096..4159.
// ---------------------------------------------------------------------------
__global__ __launch_bounds__(256) void lora_lr_kernel(const float* __restrict__ x,
                                                      const float* __restrict__ loraB,
                                                      u16* __restrict__ u) {
  __shared__ float xs[4][4096];
  __shared__ float red[4][64][4];
  int s0 = blockIdx.x * 4, t = threadIdx.x;
  const float4* xv = (const float4*)(x + (size_t)s0 * 4096);
  float4* xsv = (float4*)&xs[0][0];
#pragma unroll
  for (int j = 0; j < 16; ++j) xsv[j * 256 + t] = xv[j * 256 + t];
  __syncthreads();
  int r = t >> 2, q = t & 3;
  const float4* B4 = (const float4*)(loraB + (size_t)r * 4096 + q * 1024);
  const float4* x0 = (const float4*)&xs[0][q * 1024];
  const float4* x1 = (const float4*)&xs[1][q * 1024];
  const float4* x2 = (const float4*)&xs[2][q * 1024];
  const float4* x3 = (const float4*)&xs[3][q * 1024];
  float a0 = 0, a1 = 0, a2 = 0, a3 = 0;
#pragma unroll 4
  for (int i = 0; i < 256; ++i) {
    float4 b = B4[i];
    float4 w0 = x0[i]; a0 += b.x * w0.x + b.y * w0.y + b.z * w0.z + b.w * w0.w;
    float4 w1 = x1[i]; a1 += b.x * w1.x + b.y * w1.y + b.z * w1.z + b.w * w1.w;
    float4 w2 = x2[i]; a2 += b.x * w2.x + b.y * w2.y + b.z * w2.z + b.w * w2.w;
    float4 w3 = x3[i]; a3 += b.x * w3.x + b.y * w3.y + b.z * w3.z + b.w * w3.w;
  }
  red[0][r][q] = a0; red[1][r][q] = a1; red[2][r][q] = a2; red[3][r][q] = a3;
  __syncthreads();
  int ss = t >> 6, rr = t & 63;
  float lr = red[ss][rr][0] + red[ss][rr][1] + red[ss][rr][2] + red[ss][rr][3];
  u[(size_t)(s0 + ss) * GK + 4096 + rr] = f2bf_rne(lr);
}

// ---------------------------------------------------------------------------
// Kernel 6: GEMM z[s][m] = sum_k A[s][k]*B[m][k], K=4160, bf16 MFMA.
// 128x128 tile, BK=64, 4 waves, global_load_lds + XOR swizzle, 2-phase dbuf.
// LDS map: [0,16K) A0 | [16K,32K) A1 | [32K,48K) B0 | [48K,64K) B1.
// Swizzle f: byte bits 4-6 ^= row bits 0-2 (involution).
// ---------------------------------------------------------------------------
__device__ __forceinline__ void stage_tile(const u16* __restrict__ src, size_t rowBase,
                                           int kt, char* ldsBase, int w, int l) {
#pragma unroll
  for (int it = 0; it < 4; ++it) {
    int ci  = it * 4 + w;                 // 1KB chunk index (wave-uniform)
    int row = ci * 8 + (l >> 3);
    int cg  = (l & 7) ^ ((l >> 3) & 7);   // pre-swizzled source 16B-slot
    const u16* gp = src + (rowBase + (size_t)row) * GK + kt + cg * 8;
    __builtin_amdgcn_global_load_lds(
        (const __attribute__((address_space(1))) void*)gp,
        (__attribute__((address_space(3))) void*)(ldsBase + ci * 1024), 16, 0, 0);
  }
}

__global__ __launch_bounds__(256) void gemm_kernel(
    const u16* __restrict__ A,   // u_ext  [1024][GK]
    const u16* __restrict__ B,   // Wd_ext [4096][GK]
    float* __restrict__ Z) {     // z [1024][4096] f32 (aliases d_out)
  __shared__ char lds[65536];
  int t = threadIdx.x, w = t >> 6, l = t & 63;
  int m0 = blockIdx.x * 128, s0 = blockIdx.y * 128;
  int wm = w >> 1, wn = w & 1;
  int lr16 = l & 15, lk = l >> 4;

  floatx4 acc[4][4];
#pragma unroll
  for (int i = 0; i < 4; ++i)
#pragma unroll
    for (int j = 0; j < 4; ++j) acc[i][j] = (floatx4){0.f, 0.f, 0.f, 0.f};

  const int NT = GK / 64;   // 65
  stage_tile(A, s0, 0, lds, w, l);
  stage_tile(B, m0, 0, lds + 32768, w, l);
  asm volatile("s_waitcnt vmcnt(0)" ::: "memory");
  __builtin_amdgcn_s_barrier();

  for (int kt64 = 0; kt64 < NT; ++kt64) {
    int cur = kt64 & 1;
    if (kt64 + 1 < NT) {
      stage_tile(A, s0, (kt64 + 1) * 64, lds + (cur ^ 1) * 16384, w, l);
      stage_tile(B, m0, (kt64 + 1) * 64, lds + 32768 + (cur ^ 1) * 16384, w, l);
    }
    const char* sAc = lds + cur * 16384;
    const char* sBc = lds + 32768 + cur * 16384;
    bf16x8 a[4][2], b[4][2];
#pragma unroll
    for (int i = 0; i < 4; ++i)
#pragma unroll
      for (int ks = 0; ks < 2; ++ks) {
        int row = wm * 64 + i * 16 + lr16;
        int kb  = ks * 64 + lk * 16;
        a[i][ks] = *(const bf16x8*)(sAc + (row << 7) + (kb ^ ((row & 7) << 4)));
      }
#pragma unroll
    for (int j = 0; j < 4; ++j)
#pragma unroll
      for (int ks = 0; ks < 2; ++ks) {
        int row = wn * 64 + j * 16 + lr16;
        int kb  = ks * 64 + lk * 16;
        b[j][ks] = *(const bf16x8*)(sBc + (row << 7) + (kb ^ ((row & 7) << 4)));
      }
#pragma unroll
    for (int ks = 0; ks < 2; ++ks)
#pragma unroll
      for (int i = 0; i < 4; ++i)
#pragma unroll
        for (int j = 0; j < 4; ++j)
          acc[i][j] = __builtin_amdgcn_mfma_f32_16x16x32_bf16(a[i][ks], b[j][ks], acc[i][j], 0, 0, 0);
    asm volatile("s_waitcnt vmcnt(0)" ::: "memory");
    __builtin_amdgcn_s_barrier();
  }
  // C/D layout: col = lane&15, row = (lane>>4)*4 + q  (verified round 1)
#pragma unroll
  for (int i = 0; i < 4; ++i)
#pragma unroll
    for (int j = 0; j < 4; ++j) {
      int col  = m0 + wn * 64 + j * 16 + lr16;
      int rowb = s0 + wm * 64 + i * 16 + lk * 4;
#pragma unroll
      for (int q = 0; q < 4; ++q)
        Z[(size_t)(rowb + q) * 4096 + col] = acc[i][j][q];
    }
}

// ---------------------------------------------------------------------------
// Kernel 7: out[s][i] = (Wscale/263.68) * SV[i] * H(z[s])[i]
// z aliases out: each thread reads exactly the addresses it later writes.
// ---------------------------------------------------------------------------
__global__ __launch_bounds__(256) void final_kernel(const float* __restrict__ SV,
                                                    const float* __restrict__ WscaleP,
                                                    float* __restrict__ out) {
  __shared__ float X[4096];
  int s = blockIdx.x, t = threadIdx.x, l = t & 63, w = t >> 6;
  float* zr = out + (size_t)s * 4096;
  float v[16];
#pragma unroll
  for (int k = 0; k < 16; ++k) v[k] = zr[(w * 16 + k) * 64 + l];
  fwht4096_regs(v, X, w, l);
  float gscale = WscaleP[0] * (1.0f / 263.68f);
#pragma unroll
  for (int k = 0; k < 16; ++k) {
    int i = (w * 16 + k) * 64 + l;
    zr[i] = v[k] * gscale * SV[i];
  }
}

// ---------------------------------------------------------------------------
extern "C" void kernel_launch(void* const* d_in, const int* in_sizes, int n_in,
                              void* d_out, int out_size, void* d_ws, size_t ws_size,
                              hipStream_t stream) {
  const float* x      = (const float*)d_in[0];   // [1,1024,4096]
  const float* SU     = (const float*)d_in[1];   // [4096]
  const float* SV     = (const float*)d_in[2];   // [4096]
  const float* Wscale = (const float*)d_in[3];   // scalar
  const float* loraA  = (const float*)d_in[4];   // [4096,64]
  const float* loraB  = (const float*)d_in[5];   // [64,4096]
  const int*   Qidxs  = (const int*)d_in[6];     // [4096,512]
  const int*   grid   = (const int*)d_in[7];     // [256]
  float* out = (float*)d_out;

  char* ws = (char*)d_ws;
  u16* Wd = (u16*)ws;                                   // [4096][4160] = 34,078,720 B
  u16* u  = (u16*)(ws + 34078720);                      // [1024][4160] =  8,519,680 B
  u16* At = (u16*)(ws + 34078720 + 8519680);            // [64][4096]   =    524,288 B
  float* z = out;                                       // aliases d_out

  decode_kernel<<<8192, 256, 0, stream>>>(Qidxs, grid, Wd);
  prep_A_kernel<<<64, 256, 0, stream>>>(loraA, SV, Wscale, At);
  transA_kernel<<<64, 256, 0, stream>>>(At, Wd);
  fwht_u_kernel<<<1024, 256, 0, stream>>>(x, SU, u);
  lora_lr_kernel<<<256, 256, 0, stream>>>(x, loraB, u);
  dim3 gg(32, 8);
  gemm_kernel<<<gg, 256, 0, stream>>>(u, Wd, z);
  final_kernel<<<1024, 256, 0, stream>>>(SV, Wscale, out);
}

// Round 3
// 118.461 us; speedup vs baseline: 3.6204x; 1.0971x over previous
//
#include <hip/hip_runtime.h>
#include <hip/hip_bf16.h>

typedef unsigned short u16;
typedef float  floatx4 __attribute__((ext_vector_type(4)));
typedef short  bf16x8  __attribute__((ext_vector_type(8)));

#define GK 4224   // extended K = 4096 + 64 lora cols + 64 zero pad (2*33*64)

__device__ __forceinline__ u16 f2bf_rne(float f) {
  union { float f; unsigned int u; } v; v.f = f;
  unsigned int r = v.u + 0x7FFFu + ((v.u >> 16) & 1u);
  return (u16)(r >> 16);
}

// ===========================================================================
// In-register FWHT-4096 per block (4 waves): H4096 = H64(rows) (x) H64(cols).
// ===========================================================================
__device__ __forceinline__ void fwht4096_regs(float v[16], float* X, int w, int l) {
#pragma unroll
  for (int h = 1; h < 64; h <<= 1) {
#pragma unroll
    for (int k = 0; k < 16; ++k) {
      float o = __shfl_xor(v[k], h, 64);
      v[k] = (l & h) ? (o - v[k]) : (v[k] + o);
    }
  }
#pragma unroll
  for (int k = 0; k < 16; ++k) X[(w * 16 + k) * 64 + l] = v[k];
  __syncthreads();
  float s4 = (w & 1) ? -1.f : 1.f;
  float s5 = (w & 2) ? -1.f : 1.f;
#pragma unroll
  for (int k = 0; k < 16; ++k) {
    float x00 = X[(k     ) * 64 + l];
    float x01 = X[(k + 16) * 64 + l];
    float x10 = X[(k + 32) * 64 + l];
    float x11 = X[(k + 48) * 64 + l];
    v[k] = (x00 + s4 * x01) + s5 * (x10 + s4 * x11);
  }
#pragma unroll
  for (int h = 1; h < 16; h <<= 1) {
#pragma unroll
    for (int k = 0; k < 16; ++k) {
      if (!(k & h)) { float a = v[k], b = v[k ^ h]; v[k] = a + b; v[k ^ h] = a - b; }
    }
  }
}

// ---------------------------------------------------------------------------
// Kernel 1: decode E8P -> integer weights (exact in bf16), pitched rows of GK.
// ---------------------------------------------------------------------------
__global__ void decode_kernel(const int* __restrict__ codes,
                              const int* __restrict__ grid,
                              u16* __restrict__ Wd) {
  __shared__ int sgrid[256];
  int t = threadIdx.x;
  sgrid[t] = grid[t & 255];
  __syncthreads();
  int idx = blockIdx.x * 256 + t;            // 0 .. 4096*512-1
  int c = codes[idx];
  int abs_idx   = c & 255;
  int sign_bits = (c >> 8) & 127;
  int dlt       = 2 * ((c >> 15) & 1) - 1;   // 4*delta = ±1
  int packed    = sgrid[abs_idx];
  int par       = __popc(sign_bits) & 1;
  u16 w[8];
#pragma unroll
  for (int j = 0; j < 8; ++j) {
    int nib = (packed >> (4 * j)) & 15;
    int neg = (j < 7) ? ((sign_bits >> j) & 1) : par;
    int val = (neg ? -2 * nib : 2 * nib) + dlt;
    w[j] = f2bf_rne((float)val);             // exact: |val| <= 29
  }
  uint4 pk;
  pk.x = (unsigned)w[0] | ((unsigned)w[1] << 16);
  pk.y = (unsigned)w[2] | ((unsigned)w[3] << 16);
  pk.z = (unsigned)w[4] | ((unsigned)w[5] << 16);
  pk.w = (unsigned)w[6] | ((unsigned)w[7] << 16);
  int m = idx >> 9, g = idx & 511;
  ((uint4*)Wd)[(size_t)m * (GK / 8) + g] = pk;   // GK/8 = 528 uint4 per row
}

// ---------------------------------------------------------------------------
// Kernel 2: At[r][m] = bf16( (0.8*263.68/(4096*Wscale)) * H_M(SV o loraA[:,r]) )
// ---------------------------------------------------------------------------
__global__ __launch_bounds__(256) void prep_A_kernel(const float* __restrict__ loraA,
                                                     const float* __restrict__ SV,
                                                     const float* __restrict__ WscaleP,
                                                     u16* __restrict__ At) {
  __shared__ float X[4096];
  int r = blockIdx.x, t = threadIdx.x, l = t & 63, w = t >> 6;
  float v[16];
#pragma unroll
  for (int k = 0; k < 16; ++k) {
    int i = (w * 16 + k) * 64 + l;
    v[k] = loraA[(size_t)i * 64 + r] * SV[i];
  }
  fwht4096_regs(v, X, w, l);
  float factor = (0.8f * 263.68f / 4096.0f) / WscaleP[0];
#pragma unroll
  for (int k = 0; k < 16; ++k) {
    int i = (w * 16 + k) * 64 + l;
    At[(size_t)r * 4096 + i] = f2bf_rne(v[k] * factor);
  }
}

// ---------------------------------------------------------------------------
// Kernel 3: transpose At[64][4096] into Wd tail cols 4096..4159; zero 4160..4223
// ---------------------------------------------------------------------------
__global__ void transA_kernel(const u16* __restrict__ At, u16* __restrict__ Wd) {
  __shared__ u16 T[64][65];
  int m0 = blockIdx.x * 64, t = threadIdx.x;
  int c = t & 63, q = t >> 6;
#pragma unroll
  for (int j = 0; j < 16; ++j) {
    int r = q * 16 + j;
    T[r][c] = At[(size_t)r * 4096 + m0 + c];
  }
  __syncthreads();
#pragma unroll
  for (int j = 0; j < 16; ++j) {
    int m = q * 16 + j;
    Wd[(size_t)(m0 + m) * GK + 4096 + c] = T[c][m];
    Wd[(size_t)(m0 + m) * GK + 4160 + c] = 0;   // K pad
  }
}

// ---------------------------------------------------------------------------
// Kernel 4: u[s][0..4095] = bf16( H(x[s] o SU) / 64 )
// ---------------------------------------------------------------------------
__global__ __launch_bounds__(256) void fwht_u_kernel(const float* __restrict__ x,
                                                     const float* __restrict__ SU,
                                                     u16* __restrict__ u) {
  __shared__ float X[4096];
  int s = blockIdx.x, t = threadIdx.x, l = t & 63, w = t >> 6;
  const float* xr = x + (size_t)s * 4096;
  float v[16];
#pragma unroll
  for (int k = 0; k < 16; ++k) {
    int i = (w * 16 + k) * 64 + l;
    v[k] = xr[i] * SU[i];
  }
  fwht4096_regs(v, X, w, l);
  u16* ur = u + (size_t)s * GK;
#pragma unroll
  for (int k = 0; k < 16; ++k) {
    int i = (w * 16 + k) * 64 + l;
    ur[i] = f2bf_rne(v[k] * 0.015625f);
  }
}

// ---------------------------------------------------------------------------
// Kernel 5: lr[s,r] -> u tail cols 4096..4159 (bf16); zero pad 4160..4223.
// ---------------------------------------------------------------------------
__global__ __launch_bounds__(256) void lora_lr_kernel(const float* __restrict__ x,
                                                      const float* __restrict__ loraB,
                                                      u16* __restrict__ u) {
  __shared__ float xs[4][4096];
  __shared__ float red[4][64][4];
  int s0 = blockIdx.x * 4, t = threadIdx.x;
  const float4* xv = (const float4*)(x + (size_t)s0 * 4096);
  float4* xsv = (float4*)&xs[0][0];
#pragma unroll
  for (int j = 0; j < 16; ++j) xsv[j * 256 + t] = xv[j * 256 + t];
  __syncthreads();
  int r = t >> 2, q = t & 3;
  const float4* B4 = (const float4*)(loraB + (size_t)r * 4096 + q * 1024);
  const float4* x0 = (const float4*)&xs[0][q * 1024];
  const float4* x1 = (const float4*)&xs[1][q * 1024];
  const float4* x2 = (const float4*)&xs[2][q * 1024];
  const float4* x3 = (const float4*)&xs[3][q * 1024];
  float a0 = 0, a1 = 0, a2 = 0, a3 = 0;
#pragma unroll 4
  for (int i = 0; i < 256; ++i) {
    float4 b = B4[i];
    float4 w0 = x0[i]; a0 += b.x * w0.x + b.y * w0.y + b.z * w0.z + b.w * w0.w;
    float4 w1 = x1[i]; a1 += b.x * w1.x + b.y * w1.y + b.z * w1.z + b.w * w1.w;
    float4 w2 = x2[i]; a2 += b.x * w2.x + b.y * w2.y + b.z * w2.z + b.w * w2.w;
    float4 w3 = x3[i]; a3 += b.x * w3.x + b.y * w3.y + b.z * w3.z + b.w * w3.w;
  }
  red[0][r][q] = a0; red[1][r][q] = a1; red[2][r][q] = a2; red[3][r][q] = a3;
  __syncthreads();
  int ss = t >> 6, rr = t & 63;
  float lr = red[ss][rr][0] + red[ss][rr][1] + red[ss][rr][2] + red[ss][rr][3];
  u[(size_t)(s0 + ss) * GK + 4096 + rr] = f2bf_rne(lr);
  u[(size_t)(s0 + ss) * GK + 4160 + rr] = 0;   // K pad
}

// ---------------------------------------------------------------------------
// Kernel 6: GEMM z[s][m] = sum_k A[s][k]*B[m][k], K=4224, bf16 MFMA.
// 128x128 tile, 8 waves = 2 K-groups x (2x2 wave grid). Per group: BK=64
// double-buffered (A0|A1|B0|B1, 16KB each). Counted vmcnt(8) pipeline.
// Swizzle: 16B-slot bits (byte bits 4-6) ^= row bits 0-2 (same as verified r2).
// ---------------------------------------------------------------------------
__device__ __forceinline__ void stage64(const u16* __restrict__ src, int rowBase,
                                        int kt, char* ldsBase, int wg, int l) {
#pragma unroll
  for (int it = 0; it < 4; ++it) {
    int ci  = it * 4 + wg;                // 1KB chunk index (wave-uniform)
    int row = ci * 8 + (l >> 3);
    int cg  = (l & 7) ^ ((l >> 3) & 7);   // pre-swizzled source 16B-slot
    const u16* gp = src + (size_t)(rowBase + row) * GK + kt + cg * 8;
    __builtin_amdgcn_global_load_lds(
        (const __attribute__((address_space(1))) void*)gp,
        (__attribute__((address_space(3))) void*)(ldsBase + ci * 1024), 16, 0, 0);
  }
}

__global__ __launch_bounds__(512) void gemm_kernel(
    const u16* __restrict__ A,   // u  [1024][GK]
    const u16* __restrict__ B,   // Wd [4096][GK]
    float* __restrict__ Z) {     // z  [1024][4096] f32 (aliases d_out)
  __shared__ char lds[131072];
  int t = threadIdx.x, w = t >> 6, l = t & 63;
  int g = w >> 2, wg = w & 3;              // K-group, wave-in-group
  int m0 = blockIdx.x * 128, s0 = blockIdx.y * 128;
  int wm = wg >> 1, wn = wg & 1;
  int lr16 = l & 15, lk = l >> 4;
  char* gl = lds + g * 65536;              // group region: A0 A1 B0 B1 (16KB each)

  floatx4 acc[4][4];
#pragma unroll
  for (int i = 0; i < 4; ++i)
#pragma unroll
    for (int j = 0; j < 4; ++j) acc[i][j] = (floatx4){0.f, 0.f, 0.f, 0.f};

  const int NT2 = 33;                      // K-tiles per group (33*64 = 2112)
  int kb0 = g * 2112;

  stage64(A, s0, kb0,      gl,         wg, l);
  stage64(B, m0, kb0,      gl + 32768, wg, l);
  stage64(A, s0, kb0 + 64, gl + 16384, wg, l);
  stage64(B, m0, kb0 + 64, gl + 49152, wg, l);
  asm volatile("s_waitcnt vmcnt(8)" ::: "memory");
  __builtin_amdgcn_s_barrier();

  for (int i = 0; i < NT2; ++i) {
    int buf = i & 1;
    const char* sAc = gl + buf * 16384;
    const char* sBc = gl + 32768 + buf * 16384;
    bf16x8 a[4][2], b[4][2];
#pragma unroll
    for (int ii = 0; ii < 4; ++ii)
#pragma unroll
      for (int ks = 0; ks < 2; ++ks) {
        int row = wm * 64 + ii * 16 + lr16;
        int kb  = ks * 64 + lk * 16;
        a[ii][ks] = *(const bf16x8*)(sAc + (row << 7) + (kb ^ ((row & 7) << 4)));
      }
#pragma unroll
    for (int jj = 0; jj < 4; ++jj)
#pragma unroll
      for (int ks = 0; ks < 2; ++ks) {
        int row = wn * 64 + jj * 16 + lr16;
        int kb  = ks * 64 + lk * 16;
        b[jj][ks] = *(const bf16x8*)(sBc + (row << 7) + (kb ^ ((row & 7) << 4)));
      }
    asm volatile("s_waitcnt lgkmcnt(0)" ::: "memory");
    __builtin_amdgcn_sched_barrier(0);
    bool do_stage = (i + 2) < NT2;         // block-uniform
    if (do_stage) {
      __builtin_amdgcn_s_barrier();        // all waves done reading buf
      stage64(A, s0, kb0 + (i + 2) * 64, gl + buf * 16384, wg, l);
      stage64(B, m0, kb0 + (i + 2) * 64, gl + 32768 + buf * 16384, wg, l);
    }
#pragma unroll
    for (int ks = 0; ks < 2; ++ks)
#pragma unroll
      for (int ii = 0; ii < 4; ++ii)
#pragma unroll
        for (int jj = 0; jj < 4; ++jj)
          acc[ii][jj] = __builtin_amdgcn_mfma_f32_16x16x32_bf16(
              a[ii][ks], b[jj][ks], acc[ii][jj], 0, 0, 0);
    if (i + 1 < NT2) {
      if (do_stage) asm volatile("s_waitcnt vmcnt(8)" ::: "memory");
      else          asm volatile("s_waitcnt vmcnt(0)" ::: "memory");
      __builtin_amdgcn_s_barrier();
    }
  }

  // Cross-group reduction: group1 dumps acc into (now-free) staging LDS.
  __syncthreads();
  if (g == 1) {
#pragma unroll
    for (int ii = 0; ii < 4; ++ii)
#pragma unroll
      for (int jj = 0; jj < 4; ++jj)
        *(floatx4*)(lds + wg * 16384 + (ii * 4 + jj) * 1024 + l * 16) = acc[ii][jj];
  }
  __syncthreads();
  if (g == 0) {
#pragma unroll
    for (int ii = 0; ii < 4; ++ii)
#pragma unroll
      for (int jj = 0; jj < 4; ++jj) {
        floatx4 o = *(const floatx4*)(lds + wg * 16384 + (ii * 4 + jj) * 1024 + l * 16);
        acc[ii][jj] += o;
        int col  = m0 + wn * 64 + jj * 16 + lr16;
        int rowb = s0 + wm * 64 + ii * 16 + lk * 4;
#pragma unroll
        for (int q = 0; q < 4; ++q)
          Z[(size_t)(rowb + q) * 4096 + col] = acc[ii][jj][q];
      }
  }
}

// ---------------------------------------------------------------------------
// Kernel 7: out[s][i] = (Wscale/263.68) * SV[i] * H(z[s])[i]
// z aliases out: each thread reads exactly the addresses it later writes.
// ---------------------------------------------------------------------------
__global__ __launch_bounds__(256) void final_kernel(const float* __restrict__ SV,
                                                    const float* __restrict__ WscaleP,
                                                    float* __restrict__ out) {
  __shared__ float X[4096];
  int s = blockIdx.x, t = threadIdx.x, l = t & 63, w = t >> 6;
  float* zr = out + (size_t)s * 4096;
  float v[16];
#pragma unroll
  for (int k = 0; k < 16; ++k) v[k] = zr[(w * 16 + k) * 64 + l];
  fwht4096_regs(v, X, w, l);
  float gscale = WscaleP[0] * (1.0f / 263.68f);
#pragma unroll
  for (int k = 0; k < 16; ++k) {
    int i = (w * 16 + k) * 64 + l;
    zr[i] = v[k] * gscale * SV[i];
  }
}

// ---------------------------------------------------------------------------
extern "C" void kernel_launch(void* const* d_in, const int* in_sizes, int n_in,
                              void* d_out, int out_size, void* d_ws, size_t ws_size,
                              hipStream_t stream) {
  const float* x      = (const float*)d_in[0];   // [1,1024,4096]
  const float* SU     = (const float*)d_in[1];   // [4096]
  const float* SV     = (const float*)d_in[2];   // [4096]
  const float* Wscale = (const float*)d_in[3];   // scalar
  const float* loraA  = (const float*)d_in[4];   // [4096,64]
  const float* loraB  = (const float*)d_in[5];   // [64,4096]
  const int*   Qidxs  = (const int*)d_in[6];     // [4096,512]
  const int*   grid   = (const int*)d_in[7];     // [256]
  float* out = (float*)d_out;

  char* ws = (char*)d_ws;
  u16* Wd = (u16*)ws;                                   // [4096][4224] = 34,603,008 B
  u16* u  = (u16*)(ws + 34603008);                      // [1024][4224] =  8,650,752 B
  u16* At = (u16*)(ws + 34603008 + 8650752);            // [64][4096]   =    524,288 B
  float* z = out;                                       // aliases d_out

  decode_kernel<<<8192, 256, 0, stream>>>(Qidxs, grid, Wd);
  prep_A_kernel<<<64, 256, 0, stream>>>(loraA, SV, Wscale, At);
  transA_kernel<<<64, 256, 0, stream>>>(At, Wd);
  fwht_u_kernel<<<1024, 256, 0, stream>>>(x, SU, u);
  lora_lr_kernel<<<256, 256, 0, stream>>>(x, loraB, u);
  dim3 gg(32, 8);
  gemm_kernel<<<gg, 512, 0, stream>>>(u, Wd, z);
  final_kernel<<<1024, 256, 0, stream>>>(SV, Wscale, out);
}

// Round 4
// 95.462 us; speedup vs baseline: 4.4927x; 1.2409x over previous
//
#include <hip/hip_runtime.h>
#include <hip/hip_bf16.h>

typedef unsigned short u16;
typedef float  floatx4 __attribute__((ext_vector_type(4)));
typedef short  bf16x8  __attribute__((ext_vector_type(8)));

#define GK 4224   // extended K = 4096 + 64 lora cols + 64 zero pad (2*33*64)

__device__ __forceinline__ u16 f2bf_rne(float f) {
  union { float f; unsigned int u; } v; v.f = f;
  unsigned int r = v.u + 0x7FFFu + ((v.u >> 16) & 1u);
  return (u16)(r >> 16);
}

// ===========================================================================
// In-register FWHT-4096 per block (4 waves): H4096 = H64(rows) (x) H64(cols).
// ===========================================================================
__device__ __forceinline__ void fwht4096_regs(float v[16], float* X, int w, int l) {
#pragma unroll
  for (int h = 1; h < 64; h <<= 1) {
#pragma unroll
    for (int k = 0; k < 16; ++k) {
      float o = __shfl_xor(v[k], h, 64);
      v[k] = (l & h) ? (o - v[k]) : (v[k] + o);
    }
  }
#pragma unroll
  for (int k = 0; k < 16; ++k) X[(w * 16 + k) * 64 + l] = v[k];
  __syncthreads();
  float s4 = (w & 1) ? -1.f : 1.f;
  float s5 = (w & 2) ? -1.f : 1.f;
#pragma unroll
  for (int k = 0; k < 16; ++k) {
    float x00 = X[(k     ) * 64 + l];
    float x01 = X[(k + 16) * 64 + l];
    float x10 = X[(k + 32) * 64 + l];
    float x11 = X[(k + 48) * 64 + l];
    v[k] = (x00 + s4 * x01) + s5 * (x10 + s4 * x11);
  }
#pragma unroll
  for (int h = 1; h < 16; h <<= 1) {
#pragma unroll
    for (int k = 0; k < 16; ++k) {
      if (!(k & h)) { float a = v[k], b = v[k ^ h]; v[k] = a + b; v[k ^ h] = a - b; }
    }
  }
}

// ---------------------------------------------------------------------------
// Kernel 1: decode E8P -> integer weights (exact in bf16), pitched rows of GK.
// ---------------------------------------------------------------------------
__global__ void decode_kernel(const int* __restrict__ codes,
                              const int* __restrict__ grid,
                              u16* __restrict__ Wd) {
  __shared__ int sgrid[256];
  int t = threadIdx.x;
  sgrid[t] = grid[t & 255];
  __syncthreads();
  int idx = blockIdx.x * 256 + t;            // 0 .. 4096*512-1
  int c = codes[idx];
  int abs_idx   = c & 255;
  int sign_bits = (c >> 8) & 127;
  int dlt       = 2 * ((c >> 15) & 1) - 1;   // 4*delta = ±1
  int packed    = sgrid[abs_idx];
  int par       = __popc(sign_bits) & 1;
  u16 w[8];
#pragma unroll
  for (int j = 0; j < 8; ++j) {
    int nib = (packed >> (4 * j)) & 15;
    int neg = (j < 7) ? ((sign_bits >> j) & 1) : par;
    int val = (neg ? -2 * nib : 2 * nib) + dlt;
    w[j] = f2bf_rne((float)val);             // exact: |val| <= 29
  }
  uint4 pk;
  pk.x = (unsigned)w[0] | ((unsigned)w[1] << 16);
  pk.y = (unsigned)w[2] | ((unsigned)w[3] << 16);
  pk.z = (unsigned)w[4] | ((unsigned)w[5] << 16);
  pk.w = (unsigned)w[6] | ((unsigned)w[7] << 16);
  int m = idx >> 9, g = idx & 511;
  ((uint4*)Wd)[(size_t)m * (GK / 8) + g] = pk;   // GK/8 = 528 uint4 per row
}

// ---------------------------------------------------------------------------
// Kernel 2: At[r][m] = bf16( (0.8*263.68/(4096*Wscale)) * H_M(SV o loraA[:,r]) )
// ---------------------------------------------------------------------------
__global__ __launch_bounds__(256) void prep_A_kernel(const float* __restrict__ loraA,
                                                     const float* __restrict__ SV,
                                                     const float* __restrict__ WscaleP,
                                                     u16* __restrict__ At) {
  __shared__ float X[4096];
  int r = blockIdx.x, t = threadIdx.x, l = t & 63, w = t >> 6;
  float v[16];
#pragma unroll
  for (int k = 0; k < 16; ++k) {
    int i = (w * 16 + k) * 64 + l;
    v[k] = loraA[(size_t)i * 64 + r] * SV[i];
  }
  fwht4096_regs(v, X, w, l);
  float factor = (0.8f * 263.68f / 4096.0f) / WscaleP[0];
#pragma unroll
  for (int k = 0; k < 16; ++k) {
    int i = (w * 16 + k) * 64 + l;
    At[(size_t)r * 4096 + i] = f2bf_rne(v[k] * factor);
  }
}

// ---------------------------------------------------------------------------
// Kernel 3: transpose At[64][4096] into Wd tail cols 4096..4159; zero 4160..4223
// ---------------------------------------------------------------------------
__global__ void transA_kernel(const u16* __restrict__ At, u16* __restrict__ Wd) {
  __shared__ u16 T[64][65];
  int m0 = blockIdx.x * 64, t = threadIdx.x;
  int c = t & 63, q = t >> 6;
#pragma unroll
  for (int j = 0; j < 16; ++j) {
    int r = q * 16 + j;
    T[r][c] = At[(size_t)r * 4096 + m0 + c];
  }
  __syncthreads();
#pragma unroll
  for (int j = 0; j < 16; ++j) {
    int m = q * 16 + j;
    Wd[(size_t)(m0 + m) * GK + 4096 + c] = T[c][m];
    Wd[(size_t)(m0 + m) * GK + 4160 + c] = 0;   // K pad
  }
}

// ---------------------------------------------------------------------------
// Kernel 4: Bh[r][n] = bf16( Hnorm(loraB[r] o SU)[n] )  (orthonormal FWHT)
// lr[s,r] = x[s].loraB[r] = (x oSU).(loraB[r] oSU) = u[s].Bh[r]  (Parseval)
// ---------------------------------------------------------------------------
__global__ __launch_bounds__(256) void prep_B_kernel(const float* __restrict__ loraB,
                                                     const float* __restrict__ SU,
                                                     u16* __restrict__ Bh) {
  __shared__ float X[4096];
  int r = blockIdx.x, t = threadIdx.x, l = t & 63, w = t >> 6;
  float v[16];
#pragma unroll
  for (int k = 0; k < 16; ++k) {
    int i = (w * 16 + k) * 64 + l;
    v[k] = loraB[(size_t)r * 4096 + i] * SU[i];
  }
  fwht4096_regs(v, X, w, l);
#pragma unroll
  for (int k = 0; k < 16; ++k) {
    int i = (w * 16 + k) * 64 + l;
    Bh[(size_t)r * 4096 + i] = f2bf_rne(v[k] * 0.015625f);
  }
}

// ---------------------------------------------------------------------------
// Kernel 5: u[s][0..4095] = bf16( H(x[s] o SU) / 64 )
// ---------------------------------------------------------------------------
__global__ __launch_bounds__(256) void fwht_u_kernel(const float* __restrict__ x,
                                                     const float* __restrict__ SU,
                                                     u16* __restrict__ u) {
  __shared__ float X[4096];
  int s = blockIdx.x, t = threadIdx.x, l = t & 63, w = t >> 6;
  const float* xr = x + (size_t)s * 4096;
  float v[16];
#pragma unroll
  for (int k = 0; k < 16; ++k) {
    int i = (w * 16 + k) * 64 + l;
    v[k] = xr[i] * SU[i];
  }
  fwht4096_regs(v, X, w, l);
  u16* ur = u + (size_t)s * GK;
#pragma unroll
  for (int k = 0; k < 16; ++k) {
    int i = (w * 16 + k) * 64 + l;
    ur[i] = f2bf_rne(v[k] * 0.015625f);
  }
}

// ---------------------------------------------------------------------------
// Staging helpers (16B global_load_lds, XOR-swizzled source; verified r2/r3)
// ---------------------------------------------------------------------------
__device__ __forceinline__ void stage64(const u16* __restrict__ src, int rowBase,
                                        int kt, char* ldsBase, int wg, int l) {
#pragma unroll
  for (int it = 0; it < 4; ++it) {
    int ci  = it * 4 + wg;                // 1KB chunk index (wave-uniform)
    int row = ci * 8 + (l >> 3);
    int cg  = (l & 7) ^ ((l >> 3) & 7);   // pre-swizzled source 16B-slot
    const u16* gp = src + (size_t)(rowBase + row) * GK + kt + cg * 8;
    __builtin_amdgcn_global_load_lds(
        (const __attribute__((address_space(1))) void*)gp,
        (__attribute__((address_space(3))) void*)(ldsBase + ci * 1024), 16, 0, 0);
  }
}

// 64 rows x 64 cols, pitch 4096 (Bh)
__device__ __forceinline__ void stage64n(const u16* __restrict__ src,
                                         int kt, char* ldsBase, int wg, int l) {
#pragma unroll
  for (int it = 0; it < 2; ++it) {
    int ci  = it * 4 + wg;
    int row = ci * 8 + (l >> 3);
    int cg  = (l & 7) ^ ((l >> 3) & 7);
    const u16* gp = src + (size_t)row * 4096 + kt + cg * 8;
    __builtin_amdgcn_global_load_lds(
        (const __attribute__((address_space(1))) void*)gp,
        (__attribute__((address_space(3))) void*)(ldsBase + ci * 1024), 16, 0, 0);
  }
}

// ---------------------------------------------------------------------------
// Kernel 6: lr partials. P[by][s][r] = sum_{k in chunk by} u[s,k]*Bh[r,k]
// Grid (8 s-tiles, 4 k-chunks of 1024). 4 waves: wave w -> s rows w*32..+31.
// ---------------------------------------------------------------------------
__global__ __launch_bounds__(256) void lr_gemm_kernel(
    const u16* __restrict__ U,    // [1024][GK]
    const u16* __restrict__ Bh,   // [64][4096]
    float* __restrict__ P) {      // [4][1024][64]
  __shared__ char lds[49152];     // A0|A1 (16KB each) + B0|B1 (8KB each)
  int t = threadIdx.x, w = t >> 6, l = t & 63;
  int s0 = blockIdx.x * 128, k0 = blockIdx.y * 1024;
  int lr16 = l & 15, lk = l >> 4;
  char* ldsA = lds;
  char* ldsB = lds + 32768;

  floatx4 acc[2][4];
#pragma unroll
  for (int i = 0; i < 2; ++i)
#pragma unroll
    for (int j = 0; j < 4; ++j) acc[i][j] = (floatx4){0.f, 0.f, 0.f, 0.f};

  const int NT = 16;   // 16 * 64 = 1024
  stage64 (U,  s0, k0,      ldsA,         w, l);
  stage64n(Bh,     k0,      ldsB,         w, l);
  stage64 (U,  s0, k0 + 64, ldsA + 16384, w, l);
  stage64n(Bh,     k0 + 64, ldsB + 8192,  w, l);
  asm volatile("s_waitcnt vmcnt(6)" ::: "memory");
  __builtin_amdgcn_s_barrier();

  for (int i = 0; i < NT; ++i) {
    int buf = i & 1;
    const char* sAc = ldsA + buf * 16384;
    const char* sBc = ldsB + buf * 8192;
    bf16x8 a[2][2], b[4][2];
#pragma unroll
    for (int ii = 0; ii < 2; ++ii)
#pragma unroll
      for (int ks = 0; ks < 2; ++ks) {
        int row = w * 32 + ii * 16 + lr16;
        int kb  = ks * 64 + lk * 16;
        a[ii][ks] = *(const bf16x8*)(sAc + (row << 7) + (kb ^ ((row & 7) << 4)));
      }
#pragma unroll
    for (int jj = 0; jj < 4; ++jj)
#pragma unroll
      for (int ks = 0; ks < 2; ++ks) {
        int row = jj * 16 + lr16;
        int kb  = ks * 64 + lk * 16;
        b[jj][ks] = *(const bf16x8*)(sBc + (row << 7) + (kb ^ ((row & 7) << 4)));
      }
    asm volatile("s_waitcnt lgkmcnt(0)" ::: "memory");
    __builtin_amdgcn_sched_barrier(0);
    bool do_stage = (i + 2) < NT;
    if (do_stage) {
      __builtin_amdgcn_s_barrier();
      stage64 (U,  s0, k0 + (i + 2) * 64, ldsA + buf * 16384, w, l);
      stage64n(Bh,     k0 + (i + 2) * 64, ldsB + buf * 8192,  w, l);
    }
#pragma unroll
    for (int ks = 0; ks < 2; ++ks)
#pragma unroll
      for (int ii = 0; ii < 2; ++ii)
#pragma unroll
        for (int jj = 0; jj < 4; ++jj)
          acc[ii][jj] = __builtin_amdgcn_mfma_f32_16x16x32_bf16(
              a[ii][ks], b[jj][ks], acc[ii][jj], 0, 0, 0);
    if (i + 1 < NT) {
      if (do_stage) asm volatile("s_waitcnt vmcnt(6)" ::: "memory");
      else          asm volatile("s_waitcnt vmcnt(0)" ::: "memory");
      __builtin_amdgcn_s_barrier();
    }
  }
  float* Pb = P + (size_t)blockIdx.y * 65536;
#pragma unroll
  for (int ii = 0; ii < 2; ++ii)
#pragma unroll
    for (int jj = 0; jj < 4; ++jj) {
      int col  = jj * 16 + lr16;
      int rowb = s0 + w * 32 + ii * 16 + lk * 4;
#pragma unroll
      for (int q = 0; q < 4; ++q)
        Pb[(size_t)(rowb + q) * 64 + col] = acc[ii][jj][q];
    }
}

// ---------------------------------------------------------------------------
// Kernel 7: lr tail: u[s][4096+r] = bf16( sum_c P[c][s][r] ); zero K pad.
// ---------------------------------------------------------------------------
__global__ void lr_reduce_kernel(const float* __restrict__ P, u16* __restrict__ u) {
  int idx = blockIdx.x * 256 + threadIdx.x;   // 0..65535
  float s = P[idx] + P[65536 + idx] + P[131072 + idx] + P[196608 + idx];
  int ss = idx >> 6, rr = idx & 63;
  u[(size_t)ss * GK + 4096 + rr] = f2bf_rne(s);
  u[(size_t)ss * GK + 4160 + rr] = 0;         // K pad
}

// ---------------------------------------------------------------------------
// Kernel 8: GEMM z[s][m] = sum_k A[s][k]*B[m][k], K=4224, bf16 MFMA.
// 128x128 tile, 8 waves = 2 K-groups x (2x2). BK=64 dbuf, counted vmcnt.
// ---------------------------------------------------------------------------
__global__ __launch_bounds__(512) void gemm_kernel(
    const u16* __restrict__ A,   // u  [1024][GK]
    const u16* __restrict__ B,   // Wd [4096][GK]
    float* __restrict__ Z) {     // z  [1024][4096] f32 (aliases d_out)
  __shared__ char lds[131072];
  int t = threadIdx.x, w = t >> 6, l = t & 63;
  int g = w >> 2, wg = w & 3;              // K-group, wave-in-group
  int m0 = blockIdx.x * 128, s0 = blockIdx.y * 128;
  int wm = wg >> 1, wn = wg & 1;
  int lr16 = l & 15, lk = l >> 4;
  char* gl = lds + g * 65536;              // group region: A0 A1 B0 B1 (16KB each)

  floatx4 acc[4][4];
#pragma unroll
  for (int i = 0; i < 4; ++i)
#pragma unroll
    for (int j = 0; j < 4; ++j) acc[i][j] = (floatx4){0.f, 0.f, 0.f, 0.f};

  const int NT2 = 33;                      // K-tiles per group (33*64 = 2112)
  int kb0 = g * 2112;

  stage64(A, s0, kb0,      gl,         wg, l);
  stage64(B, m0, kb0,      gl + 32768, wg, l);
  stage64(A, s0, kb0 + 64, gl + 16384, wg, l);
  stage64(B, m0, kb0 + 64, gl + 49152, wg, l);
  asm volatile("s_waitcnt vmcnt(8)" ::: "memory");
  __builtin_amdgcn_s_barrier();

  for (int i = 0; i < NT2; ++i) {
    int buf = i & 1;
    const char* sAc = gl + buf * 16384;
    const char* sBc = gl + 32768 + buf * 16384;
    bf16x8 a[4][2], b[4][2];
#pragma unroll
    for (int ii = 0; ii < 4; ++ii)
#pragma unroll
      for (int ks = 0; ks < 2; ++ks) {
        int row = wm * 64 + ii * 16 + lr16;
        int kb  = ks * 64 + lk * 16;
        a[ii][ks] = *(const bf16x8*)(sAc + (row << 7) + (kb ^ ((row & 7) << 4)));
      }
#pragma unroll
    for (int jj = 0; jj < 4; ++jj)
#pragma unroll
      for (int ks = 0; ks < 2; ++ks) {
        int row = wn * 64 + jj * 16 + lr16;
        int kb  = ks * 64 + lk * 16;
        b[jj][ks] = *(const bf16x8*)(sBc + (row << 7) + (kb ^ ((row & 7) << 4)));
      }
    asm volatile("s_waitcnt lgkmcnt(0)" ::: "memory");
    __builtin_amdgcn_sched_barrier(0);
    bool do_stage = (i + 2) < NT2;         // block-uniform
    if (do_stage) {
      __builtin_amdgcn_s_barrier();        // all waves done reading buf
      stage64(A, s0, kb0 + (i + 2) * 64, gl + buf * 16384, wg, l);
      stage64(B, m0, kb0 + (i + 2) * 64, gl + 32768 + buf * 16384, wg, l);
    }
#pragma unroll
    for (int ks = 0; ks < 2; ++ks)
#pragma unroll
      for (int ii = 0; ii < 4; ++ii)
#pragma unroll
        for (int jj = 0; jj < 4; ++jj)
          acc[ii][jj] = __builtin_amdgcn_mfma_f32_16x16x32_bf16(
              a[ii][ks], b[jj][ks], acc[ii][jj], 0, 0, 0);
    if (i + 1 < NT2) {
      if (do_stage) asm volatile("s_waitcnt vmcnt(8)" ::: "memory");
      else          asm volatile("s_waitcnt vmcnt(0)" ::: "memory");
      __builtin_amdgcn_s_barrier();
    }
  }

  // Cross-group reduction: group1 dumps acc into (now-free) staging LDS.
  __syncthreads();
  if (g == 1) {
#pragma unroll
    for (int ii = 0; ii < 4; ++ii)
#pragma unroll
      for (int jj = 0; jj < 4; ++jj)
        *(floatx4*)(lds + wg * 16384 + (ii * 4 + jj) * 1024 + l * 16) = acc[ii][jj];
  }
  __syncthreads();
  if (g == 0) {
#pragma unroll
    for (int ii = 0; ii < 4; ++ii)
#pragma unroll
      for (int jj = 0; jj < 4; ++jj) {
        floatx4 o = *(const floatx4*)(lds + wg * 16384 + (ii * 4 + jj) * 1024 + l * 16);
        acc[ii][jj] += o;
        int col  = m0 + wn * 64 + jj * 16 + lr16;
        int rowb = s0 + wm * 64 + ii * 16 + lk * 4;
#pragma unroll
        for (int q = 0; q < 4; ++q)
          Z[(size_t)(rowb + q) * 4096 + col] = acc[ii][jj][q];
      }
  }
}

// ---------------------------------------------------------------------------
// Kernel 9: out[s][i] = (Wscale/263.68) * SV[i] * H(z[s])[i]
// ---------------------------------------------------------------------------
__global__ __launch_bounds__(256) void final_kernel(const float* __restrict__ SV,
                                                    const float* __restrict__ WscaleP,
                                                    float* __restrict__ out) {
  __shared__ float X[4096];
  int s = blockIdx.x, t = threadIdx.x, l = t & 63, w = t >> 6;
  float* zr = out + (size_t)s * 4096;
  float v[16];
#pragma unroll
  for (int k = 0; k < 16; ++k) v[k] = zr[(w * 16 + k) * 64 + l];
  fwht4096_regs(v, X, w, l);
  float gscale = WscaleP[0] * (1.0f / 263.68f);
#pragma unroll
  for (int k = 0; k < 16; ++k) {
    int i = (w * 16 + k) * 64 + l;
    zr[i] = v[k] * gscale * SV[i];
  }
}

// ---------------------------------------------------------------------------
extern "C" void kernel_launch(void* const* d_in, const int* in_sizes, int n_in,
                              void* d_out, int out_size, void* d_ws, size_t ws_size,
                              hipStream_t stream) {
  const float* x      = (const float*)d_in[0];   // [1,1024,4096]
  const float* SU     = (const float*)d_in[1];   // [4096]
  const float* SV     = (const float*)d_in[2];   // [4096]
  const float* Wscale = (const float*)d_in[3];   // scalar
  const float* loraA  = (const float*)d_in[4];   // [4096,64]
  const float* loraB  = (const float*)d_in[5];   // [64,4096]
  const int*   Qidxs  = (const int*)d_in[6];     // [4096,512]
  const int*   grid   = (const int*)d_in[7];     // [256]
  float* out = (float*)d_out;

  char* ws = (char*)d_ws;
  u16* Wd = (u16*)ws;                                   // [4096][4224] = 34,603,008 B
  u16* u  = (u16*)(ws + 34603008);                      // [1024][4224] =  8,650,752 B
  u16* At = (u16*)(ws + 34603008 + 8650752);            // [64][4096]   =    524,288 B
  u16* Bh = At;                                         // reused after transA
  float* P = (float*)(ws + 34603008 + 8650752 + 524288);// [4][1024][64] = 1,048,576 B
  float* z = out;                                       // aliases d_out

  decode_kernel<<<8192, 256, 0, stream>>>(Qidxs, grid, Wd);
  prep_A_kernel<<<64, 256, 0, stream>>>(loraA, SV, Wscale, At);
  transA_kernel<<<64, 256, 0, stream>>>(At, Wd);
  prep_B_kernel<<<64, 256, 0, stream>>>(loraB, SU, Bh);   // At slot now free
  fwht_u_kernel<<<1024, 256, 0, stream>>>(x, SU, u);
  dim3 lg(8, 4);
  lr_gemm_kernel<<<lg, 256, 0, stream>>>(u, Bh, P);
  lr_reduce_kernel<<<256, 256, 0, stream>>>(P, u);
  dim3 gg(32, 8);
  gemm_kernel<<<gg, 512, 0, stream>>>(u, Wd, z);
  final_kernel<<<1024, 256, 0, stream>>>(SV, Wscale, out);
}